// Round 9
// baseline (362.016 us; speedup 1.0000x reference)
//
#include <hip/hip_runtime.h>

#define KOFF 9
#define N_PTS 262144
#define D 32
#define BINS 512
#define ROWS_PER_BIN 512       // N_PTS / BINS
#define TILE_ROWS 513          // + dump row for sentinel entries
#define CAP 640                // per (bin,k) bucket capacity
#define OVER_CAP 131072
#define SENT (512u << 18)

typedef __attribute__((ext_vector_type(4))) float f32x4;
typedef __attribute__((ext_vector_type(8))) short short8;

__device__ inline short f2bf(float f) {      // round-to-nearest-even f32->bf16
    unsigned u = __float_as_uint(f);
    u = (u + 0x7fffu + ((u >> 16) & 1u)) >> 16;
    return (short)u;
}

// ---------- feat f32 -> bf16 (streaming, 8 elems/thread) ----------
__global__ void __launch_bounds__(256)
convert_kernel(const float* __restrict__ feat, unsigned short* __restrict__ bfeat) {
    int i = blockIdx.x * 256 + threadIdx.x;
    const f32x4* f4 = (const f32x4*)feat;
    f32x4 a = f4[2 * i], b = f4[2 * i + 1];
    short8 o;
#pragma unroll
    for (int j = 0; j < 4; ++j) { o[j] = f2bf(a[j]); o[j + 4] = f2bf(b[j]); }
    *(short8*)(bfeat + (size_t)i * 8) = o;
}

// ---------- fill: bin pairs by (orow>>9, k); entry = irow | olow<<18 ----------
__global__ void __launch_bounds__(256)
fill_kernel(const int* __restrict__ indice_pairs,
            const int* __restrict__ indice_pair_num,
            int* __restrict__ counts,          // [BINS*KOFF]
            unsigned int* __restrict__ buckets,
            uint2* __restrict__ overlist,
            int* __restrict__ over_n) {
    const int k = blockIdx.y;
    const int n_k = indice_pair_num[k];
    if (blockIdx.x * 256 >= n_k) return;
    const int p = blockIdx.x * 256 + threadIdx.x;
    if (p >= n_k) return;
    int irow = indice_pairs[(size_t)k * N_PTS + p];
    int orow = indice_pairs[(size_t)(KOFF + k) * N_PTS + p];
    int bin = orow >> 9, olow = orow & 511;
    int b = bin * KOFF + k;
    int slot = atomicAdd(&counts[b], 1);
    if (slot < CAP) {
        buckets[(size_t)b * CAP + slot] = (unsigned)irow | ((unsigned)olow << 18);
    } else {
        int s2 = atomicAdd(over_n, 1);
        if (s2 < OVER_CAP) overlist[s2] = make_uint2((unsigned)irow | ((unsigned)k << 18),
                                                     (unsigned)orow);
    }
}

// ---------- phase 2: per-bin LDS-tile accumulate with MFMA ----------
// unsafeAtomicAdd -> native ds_add_f32 (no CAS loop). That CAS loop is the
// hypothesized invariant ~133 cy/DS-instr cost pinning phase2 at 192 us R4-R7.
template<int BF16>
__global__ void __launch_bounds__(512, 4)
phase2_kernel(const float* __restrict__ feat,
              const unsigned short* __restrict__ bfeat,
              const float* __restrict__ weight,
              const float* __restrict__ bias,
              const int* __restrict__ counts,
              const unsigned int* __restrict__ buckets,
              float* __restrict__ out) {
    __shared__ f32x4 tile4[TILE_ROWS * D / 4];      // 65,664 B accumulator
    float* tile = (float*)tile4;

    const int bin  = blockIdx.x;
    const int tid  = threadIdx.x;
    const int wave = tid >> 6;
    const int lane = tid & 63;

    f32x4 z = {0.f, 0.f, 0.f, 0.f};
    for (int i = tid; i < TILE_ROWS * D / 4; i += 512) tile4[i] = z;
    __syncthreads();

    const int arow = lane & 15;                 // A row / entry index within group
    const int hoff = (lane >> 4) << 3;          // k-dim chunk: 8 elems

#pragma unroll 1
    for (int k = 0; k < KOFF; ++k) {
        // B fragments: B[c=hoff+j][col=arow(+16)] = weight[col][k][c]
        short8 bf0, bf1;
        {
            const float* wp0 = weight + (size_t)arow * (KOFF * D) + k * D + hoff;
            const float* wp1 = wp0 + 16 * (KOFF * D);
            f32x4 w0 = *(const f32x4*)wp0, w1 = *(const f32x4*)(wp0 + 4);
            f32x4 w2 = *(const f32x4*)wp1, w3 = *(const f32x4*)(wp1 + 4);
#pragma unroll
            for (int j = 0; j < 4; ++j) {
                bf0[j] = f2bf(w0[j]); bf0[j + 4] = f2bf(w1[j]);
                bf1[j] = f2bf(w2[j]); bf1[j + 4] = f2bf(w3[j]);
            }
        }

        int cnt = counts[bin * KOFF + k];
        cnt = cnt < CAP ? cnt : CAP;
        const unsigned* bk = buckets + (size_t)(bin * KOFF + k) * CAP;
        int ngroups = (cnt + 15) >> 4;

        // depth-2 pipeline
        unsigned entA = SENT;
        short8 afA = {0, 0, 0, 0, 0, 0, 0, 0};
        f32x4 fa0 = z, fa1 = z;
        int g = wave;
        if (g < ngroups) {
            int ei = g * 16 + arow;
            entA = (ei < cnt) ? bk[ei] : SENT;
            if constexpr (BF16) {
                afA = *(const short8*)(bfeat + ((size_t)(entA & 0x3ffff) << 5) + hoff);
            } else {
                const float* fp = feat + ((size_t)(entA & 0x3ffff) << 5) + hoff;
                fa0 = *(const f32x4*)fp; fa1 = *(const f32x4*)(fp + 4);
            }
        }
#pragma unroll 1
        for (; g < ngroups; g += 8) {
            unsigned entB = SENT;
            short8 afB = {0, 0, 0, 0, 0, 0, 0, 0};
            f32x4 fb0 = z, fb1 = z;
            int gn = g + 8;
            if (gn < ngroups) {
                int ei = gn * 16 + arow;
                entB = (ei < cnt) ? bk[ei] : SENT;
                if constexpr (BF16) {
                    afB = *(const short8*)(bfeat + ((size_t)(entB & 0x3ffff) << 5) + hoff);
                } else {
                    const float* fp = feat + ((size_t)(entB & 0x3ffff) << 5) + hoff;
                    fb0 = *(const f32x4*)fp; fb1 = *(const f32x4*)(fp + 4);
                }
            }

            short8 af;
            if constexpr (BF16) {
                af = afA;
            } else {
#pragma unroll
                for (int j = 0; j < 4; ++j) { af[j] = f2bf(fa0[j]); af[j + 4] = f2bf(fa1[j]); }
            }

            f32x4 acc0 = __builtin_amdgcn_mfma_f32_16x16x32_bf16(af, bf0, z, 0, 0, 0);
            f32x4 acc1 = __builtin_amdgcn_mfma_f32_16x16x32_bf16(af, bf1, z, 0, 0, 0);

            // scatter C: row=(lane>>4)*4+rg entries, cols arow & arow+16
#pragma unroll
            for (int rg = 0; rg < 4; ++rg) {
                int crow = ((lane >> 4) << 2) + rg;
                int entc = __builtin_amdgcn_ds_bpermute(crow << 2, (int)entA);
                int rl   = ((unsigned)entc >> 18) & 0x3ff;
                int sw   = ((rl >> 2) & 1) << 4;
                unsafeAtomicAdd(&tile[rl * D + (arow ^ sw)], acc0[rg]);
                unsafeAtomicAdd(&tile[rl * D + ((arow + 16) ^ sw)], acc1[rg]);
            }
            entA = entB; afA = afB; fa0 = fb0; fa1 = fb1;
        }
    }
    __syncthreads();

    // stream tile + bias to out (coalesced, unswizzled)
    f32x4 b4 = ((const f32x4*)bias)[tid & 7];
    for (int i = tid; i < ROWS_PER_BIN * 8; i += 512) {
        int row = i >> 3, c4 = i & 7;
        int sc4 = c4 ^ (((row >> 2) & 1) << 2);     // f32x4-level unswizzle
        f32x4 v = tile4[row * 8 + sc4];
        v += b4;
        *(f32x4*)&out[((size_t)(bin * ROWS_PER_BIN + row)) * D + c4 * 4] = v;
    }
}

// ---------- rare overflow cleanup (after phase2 store) ----------
__global__ void overflow_kernel(const float* __restrict__ feat,
                                const float* __restrict__ weight,
                                const uint2* __restrict__ overlist,
                                const int* __restrict__ over_n,
                                float* __restrict__ out) {
    int n = *over_n;
    n = n < OVER_CAP ? n : OVER_CAP;
    for (int i = blockIdx.x * blockDim.x + threadIdx.x; i < n;
         i += gridDim.x * blockDim.x) {
        uint2 e = overlist[i];
        int irow = e.x & 0x3ffff, k = (e.x >> 18) & 15, orow = (int)e.y;
        float fr[D];
#pragma unroll
        for (int c = 0; c < D; c += 4)
            *(f32x4*)&fr[c] = *(const f32x4*)&feat[(size_t)irow * D + c];
#pragma unroll 1
        for (int dd = 0; dd < D; ++dd) {
            float a = 0.f;
#pragma unroll
            for (int c = 0; c < D; ++c)
                a += fr[c] * weight[dd * (KOFF * D) + k * D + c];
            unsafeAtomicAdd(&out[(size_t)orow * D + dd], a);
        }
    }
}

// ---------- fallback path (R1): direct scatter with global atomics ----------
__global__ void bias_init_kernel(const float* __restrict__ bias,
                                 float* __restrict__ out) {
    int i = blockIdx.x * blockDim.x + threadIdx.x;
    float4 b = ((const float4*)bias)[i & 7];
    ((float4*)out)[i] = b;
}

#define PPB 8
__global__ void __launch_bounds__(256)
scatter_conv_kernel(const float* __restrict__ feat,
                    const float* __restrict__ weight,
                    const int* __restrict__ indice_pairs,
                    const int* __restrict__ indice_pair_num,
                    float* __restrict__ out) {
    const int k   = blockIdx.y;
    const int n_k = indice_pair_num[k];
    const int p0  = blockIdx.x * PPB;
    if (p0 >= n_k) return;
    __shared__ float w[D][D];
    __shared__ float f[PPB][D];
    for (int idx = threadIdx.x; idx < D * D; idx += 256) {
        int c = idx >> 5, d = idx & 31;
        w[c][d] = weight[d * (KOFF * D) + k * D + c];
    }
    const int pp = threadIdx.x >> 5;
    const int d  = threadIdx.x & 31;
    const int p  = p0 + pp;
    int orow = -1;
    if (p < n_k) {
        int irow = indice_pairs[(size_t)k * N_PTS + p];
        orow     = indice_pairs[(size_t)(KOFF + k) * N_PTS + p];
        f[pp][d] = feat[(size_t)irow * D + d];
    }
    __syncthreads();
    if (p < n_k) {
        float acc = 0.f;
#pragma unroll
        for (int c = 0; c < D; ++c) acc += f[pp][c] * w[c][d];
        unsafeAtomicAdd(&out[(size_t)orow * D + d], acc);
    }
}

extern "C" void kernel_launch(void* const* d_in, const int* in_sizes, int n_in,
                              void* d_out, int out_size, void* d_ws, size_t ws_size,
                              hipStream_t stream) {
    const float* feat            = (const float*)d_in[0];
    const float* weight          = (const float*)d_in[1];
    const float* bias            = (const float*)d_in[2];
    const int*   indice_pairs    = (const int*)d_in[3];
    const int*   indice_pair_num = (const int*)d_in[4];
    float*       out             = (float*)d_out;

    const size_t HDR   = 32768;                           // counts(18,432) + over_n
    const size_t BKT   = (size_t)BINS * KOFF * CAP * 4;   // 11.25 MiB
    const size_t OVERB = (size_t)OVER_CAP * 8;            // 1 MiB
    const size_t FEATB = (size_t)N_PTS * D * 2;           // 16 MiB bf16 feat
    const size_t need_bf  = FEATB + HDR + BKT + OVERB;    // ~28.3 MiB
    const size_t need_f32 = HDR + BKT + OVERB;            // ~12.3 MiB

    if (ws_size >= need_bf) {
        unsigned short* bfeat = (unsigned short*)d_ws;
        char* base = (char*)d_ws + FEATB;
        int*          counts   = (int*)base;
        int*          over_n   = (int*)(base + 20480);
        unsigned int* buckets  = (unsigned int*)(base + HDR);
        uint2*        overlist = (uint2*)(base + HDR + BKT);

        hipMemsetAsync(base, 0, HDR, stream);
        convert_kernel<<<N_PTS * D / 8 / 256, 256, 0, stream>>>(feat, bfeat);
        dim3 fgrid(N_PTS / 256, KOFF);
        fill_kernel<<<fgrid, 256, 0, stream>>>(indice_pairs, indice_pair_num,
                                               counts, buckets, overlist, over_n);
        phase2_kernel<1><<<BINS, 512, 0, stream>>>(feat, bfeat, weight, bias,
                                                   counts, buckets, out);
        overflow_kernel<<<64, 256, 0, stream>>>(feat, weight, overlist, over_n, out);
    } else if (ws_size >= need_f32) {
        int*          counts   = (int*)d_ws;
        int*          over_n   = (int*)((char*)d_ws + 20480);
        unsigned int* buckets  = (unsigned int*)((char*)d_ws + HDR);
        uint2*        overlist = (uint2*)((char*)d_ws + HDR + BKT);

        hipMemsetAsync(d_ws, 0, HDR, stream);
        dim3 fgrid(N_PTS / 256, KOFF);
        fill_kernel<<<fgrid, 256, 0, stream>>>(indice_pairs, indice_pair_num,
                                               counts, buckets, overlist, over_n);
        phase2_kernel<0><<<BINS, 512, 0, stream>>>(feat, nullptr, weight, bias,
                                                   counts, buckets, out);
        overflow_kernel<<<64, 256, 0, stream>>>(feat, weight, overlist, over_n, out);
    } else {
        int n_vec4 = N_PTS * D / 4;
        bias_init_kernel<<<n_vec4 / 256, 256, 0, stream>>>(bias, out);
        dim3 grid((N_PTS + PPB - 1) / PPB, KOFF);
        scatter_conv_kernel<<<grid, 256, 0, stream>>>(
            feat, weight, indice_pairs, indice_pair_num, out);
    }
}

// Round 10
// 314.074 us; speedup vs baseline: 1.1526x; 1.1526x over previous
//
#include <hip/hip_runtime.h>

#define KOFF 9
#define N_PTS 262144
#define D 32
#define RCAP 16                 // per-output-row bucket capacity
#define OVER_CAP 131072

typedef __attribute__((ext_vector_type(4))) float f32x4;
typedef __attribute__((ext_vector_type(8))) short short8;

__device__ inline short f2bf(float f) {      // round-to-nearest-even f32->bf16
    unsigned u = __float_as_uint(f);
    u = (u + 0x7fffu + ((u >> 16) & 1u)) >> 16;
    return (short)u;
}

// ---------- fill: bucket pairs by OUTPUT ROW; entry = (k<<18)|irow ----------
__global__ void __launch_bounds__(256)
fill_row_kernel(const int* __restrict__ indice_pairs,
                const int* __restrict__ indice_pair_num,
                int* __restrict__ counts,          // [N_PTS]
                unsigned int* __restrict__ buckets,// [N_PTS][RCAP]
                uint2* __restrict__ overlist,
                int* __restrict__ over_n) {
    const int k = blockIdx.y;
    const int n_k = indice_pair_num[k];
    if (blockIdx.x * 256 >= n_k) return;
    const int p = blockIdx.x * 256 + threadIdx.x;
    if (p >= n_k) return;
    int irow = indice_pairs[(size_t)k * N_PTS + p];
    int orow = indice_pairs[(size_t)(KOFF + k) * N_PTS + p];
    unsigned ent = ((unsigned)k << 18) | (unsigned)irow;
    int slot = atomicAdd(&counts[orow], 1);
    if (slot < RCAP) {
        buckets[(size_t)orow * RCAP + slot] = ent;
    } else {
        int s2 = atomicAdd(over_n, 1);
        if (s2 < OVER_CAP) overlist[s2] = make_uint2(ent, (unsigned)orow);
    }
}

// ---------- rowgemm: output-stationary, zero atomics, zero bpermute ----------
// Wave owns 16 consecutive output rows. Entries counting-placed by k into a
// wave-private LDS strip; per k: C += gathered_feat @ W_k via MFMA, C in regs
// (initialized with bias), single coalesced store.
__global__ void __launch_bounds__(512)
rowgemm_kernel(const float* __restrict__ feat,
               const float* __restrict__ weight,
               const float* __restrict__ bias,
               const int* __restrict__ counts,
               const unsigned int* __restrict__ buckets,
               float* __restrict__ out) {
    __shared__ unsigned slds[8 * 16 * RCAP];        // 8 KB: [wave][rowslot][16]
    const int tid  = threadIdx.x;
    const int wave = tid >> 6;
    const int lane = tid & 63;
    const int c    = lane >> 4;                     // k-chunk 0..3
    const int s    = lane & 15;                     // rowslot / out channel
    const int hoff = c << 3;                        // 8 floats per chunk
    const int r0   = blockIdx.x * 128 + wave * 16;
    const int r    = r0 + s;

    int cnt = counts[r];
    cnt = cnt < RCAP ? cnt : RCAP;

    unsigned e[16];
    {
        const uint4* b4 = (const uint4*)(buckets + (size_t)r * RCAP);
        uint4 q0 = b4[0], q1 = b4[1], q2 = b4[2], q3 = b4[3];
        e[0]=q0.x; e[1]=q0.y; e[2]=q0.z; e[3]=q0.w;
        e[4]=q1.x; e[5]=q1.y; e[6]=q1.z; e[7]=q1.w;
        e[8]=q2.x; e[9]=q2.y; e[10]=q2.z; e[11]=q2.w;
        e[12]=q3.x; e[13]=q3.y; e[14]=q3.z; e[15]=q3.w;
    }
#pragma unroll
    for (int i = 0; i < 16; ++i)
        if (i >= cnt) e[i] = 0xFFFFFFFFu;           // pad sorts beyond k=8

    unsigned ky[16];
#pragma unroll
    for (int i = 0; i < 16; ++i) ky[i] = e[i] >> 18;

    // counting placement (stable, correctness-trivial) into LDS strip
    unsigned* myrow = slds + wave * 256 + s * 16;
#pragma unroll
    for (int i = 0; i < 16; ++i) {
        int pos = 0;
#pragma unroll
        for (int j = 0; j < 16; ++j) {
            if (j < i)      pos += (ky[j] <= ky[i]);
            else if (j > i) pos += (ky[j] <  ky[i]);
        }
        if (c == 0) myrow[pos] = e[i];              // runtime LDS addr: fine
    }

    int offs[10];                                    // static-indexed only
    offs[0] = 0;
#pragma unroll
    for (int k = 1; k <= 9; ++k) {
        int o = 0;
#pragma unroll
        for (int i = 0; i < 16; ++i) o += (ky[i] < (unsigned)k);
        offs[k] = o;
    }

    float b0 = bias[s], b1 = bias[s + 16];
    f32x4 acc0 = {b0, b0, b0, b0};                  // C init = bias
    f32x4 acc1 = {b1, b1, b1, b1};
    const short8 z8 = {0, 0, 0, 0, 0, 0, 0, 0};

#pragma unroll
    for (int k = 0; k < KOFF; ++k) {
        int ckl = offs[k + 1] - offs[k];            // this row's k-count
        int m = ckl;                                 // wave max -> iter bound
#pragma unroll
        for (int d = 1; d < 64; d <<= 1) {
            int t = __shfl_xor(m, d);
            m = m > t ? m : t;
        }
        if (m > 0) {
            // B frags: B[ch=hoff+j][col=s(+16)] = weight[col][k][ch]
            const float* wp0 = weight + (size_t)s * (KOFF * D) + k * D + hoff;
            const float* wp1 = wp0 + 16 * (KOFF * D);
            f32x4 w0 = *(const f32x4*)wp0, w1 = *(const f32x4*)(wp0 + 4);
            f32x4 w2 = *(const f32x4*)wp1, w3 = *(const f32x4*)(wp1 + 4);
            short8 bfa, bfb;
#pragma unroll
            for (int j = 0; j < 4; ++j) {
                bfa[j] = f2bf(w0[j]); bfa[j + 4] = f2bf(w1[j]);
                bfb[j] = f2bf(w2[j]); bfb[j + 4] = f2bf(w3[j]);
            }

            const int p0i = offs[k];
            unsigned entA = myrow[p0i & 15];
            int irA = entA & 0x3ffff;
            const float* fpA = feat + (size_t)irA * D + hoff;
            f32x4 fa0 = *(const f32x4*)fpA, fa1 = *(const f32x4*)(fpA + 4);
#pragma unroll 1
            for (int i = 0; i < m; ++i) {
                unsigned entB = myrow[(p0i + i + 1) & 15];   // depth-2 prefetch
                int irB = entB & 0x3ffff;
                const float* fpB = feat + (size_t)irB * D + hoff;
                f32x4 fb0 = *(const f32x4*)fpB, fb1 = *(const f32x4*)(fpB + 4);

                short8 af;
#pragma unroll
                for (int j = 0; j < 4; ++j) { af[j] = f2bf(fa0[j]); af[j + 4] = f2bf(fa1[j]); }
                if (i >= ckl) af = z8;               // masked row-slot

                acc0 = __builtin_amdgcn_mfma_f32_16x16x32_bf16(af, bfa, acc0, 0, 0, 0);
                acc1 = __builtin_amdgcn_mfma_f32_16x16x32_bf16(af, bfb, acc1, 0, 0, 0);
                entA = entB; fa0 = fb0; fa1 = fb1;
            }
        }
    }

    // store C: row=(lane>>4)*4+g, col=s / s+16  (verified layout, m89)
#pragma unroll
    for (int g = 0; g < 4; ++g) {
        int row = r0 + c * 4 + g;
        out[(size_t)row * D + s]      = acc0[g];
        out[(size_t)row * D + s + 16] = acc1[g];
    }
}

// ---------- rare overflow cleanup (after rowgemm store) ----------
__global__ void overflow_kernel(const float* __restrict__ feat,
                                const float* __restrict__ weight,
                                const uint2* __restrict__ overlist,
                                const int* __restrict__ over_n,
                                float* __restrict__ out) {
    int n = *over_n;
    n = n < OVER_CAP ? n : OVER_CAP;
    for (int i = blockIdx.x * blockDim.x + threadIdx.x; i < n;
         i += gridDim.x * blockDim.x) {
        uint2 ev = overlist[i];
        int irow = ev.x & 0x3ffff, k = (ev.x >> 18) & 15, orow = (int)ev.y;
        float fr[D];
#pragma unroll
        for (int ch = 0; ch < D; ch += 4)
            *(f32x4*)&fr[ch] = *(const f32x4*)&feat[(size_t)irow * D + ch];
#pragma unroll 1
        for (int dd = 0; dd < D; ++dd) {
            float a = 0.f;
#pragma unroll
            for (int ch = 0; ch < D; ++ch)
                a += fr[ch] * weight[dd * (KOFF * D) + k * D + ch];
            unsafeAtomicAdd(&out[(size_t)orow * D + dd], a);
        }
    }
}

// ---------- fallback path (R1): direct scatter with global atomics ----------
__global__ void bias_init_kernel(const float* __restrict__ bias,
                                 float* __restrict__ out) {
    int i = blockIdx.x * blockDim.x + threadIdx.x;
    float4 b = ((const float4*)bias)[i & 7];
    ((float4*)out)[i] = b;
}

#define PPB 8
__global__ void __launch_bounds__(256)
scatter_conv_kernel(const float* __restrict__ feat,
                    const float* __restrict__ weight,
                    const int* __restrict__ indice_pairs,
                    const int* __restrict__ indice_pair_num,
                    float* __restrict__ out) {
    const int k   = blockIdx.y;
    const int n_k = indice_pair_num[k];
    const int p0  = blockIdx.x * PPB;
    if (p0 >= n_k) return;
    __shared__ float w[D][D];
    __shared__ float f[PPB][D];
    for (int idx = threadIdx.x; idx < D * D; idx += 256) {
        int ch = idx >> 5, d = idx & 31;
        w[ch][d] = weight[d * (KOFF * D) + k * D + ch];
    }
    const int pp = threadIdx.x >> 5;
    const int d  = threadIdx.x & 31;
    const int p  = p0 + pp;
    int orow = -1;
    if (p < n_k) {
        int irow = indice_pairs[(size_t)k * N_PTS + p];
        orow     = indice_pairs[(size_t)(KOFF + k) * N_PTS + p];
        f[pp][d] = feat[(size_t)irow * D + d];
    }
    __syncthreads();
    if (p < n_k) {
        float acc = 0.f;
#pragma unroll
        for (int ch = 0; ch < D; ++ch) acc += f[pp][ch] * w[ch][d];
        unsafeAtomicAdd(&out[(size_t)orow * D + d], acc);
    }
}

extern "C" void kernel_launch(void* const* d_in, const int* in_sizes, int n_in,
                              void* d_out, int out_size, void* d_ws, size_t ws_size,
                              hipStream_t stream) {
    const float* feat            = (const float*)d_in[0];
    const float* weight          = (const float*)d_in[1];
    const float* bias            = (const float*)d_in[2];
    const int*   indice_pairs    = (const int*)d_in[3];
    const int*   indice_pair_num = (const int*)d_in[4];
    float*       out             = (float*)d_out;

    const size_t CNTB  = (size_t)N_PTS * 4;               // 1 MiB counts
    const size_t HDR   = CNTB + 4096;                     // + over_n page
    const size_t BKT   = (size_t)N_PTS * RCAP * 4;        // 16 MiB buckets
    const size_t OVERB = (size_t)OVER_CAP * 8;            // 1 MiB
    const size_t need  = HDR + BKT + OVERB;               // ~18.1 MiB

    if (ws_size >= need) {
        int*          cnts     = (int*)d_ws;
        int*          over_n   = (int*)((char*)d_ws + CNTB);
        unsigned int* buckets  = (unsigned int*)((char*)d_ws + HDR);
        uint2*        overlist = (uint2*)((char*)d_ws + HDR + BKT);

        hipMemsetAsync(d_ws, 0, HDR, stream);
        dim3 fgrid(N_PTS / 256, KOFF);
        fill_row_kernel<<<fgrid, 256, 0, stream>>>(indice_pairs, indice_pair_num,
                                                   cnts, buckets, overlist, over_n);
        rowgemm_kernel<<<N_PTS / 128, 512, 0, stream>>>(feat, weight, bias,
                                                        cnts, buckets, out);
        overflow_kernel<<<64, 256, 0, stream>>>(feat, weight, overlist, over_n, out);
    } else {
        int n_vec4 = N_PTS * D / 4;
        bias_init_kernel<<<n_vec4 / 256, 256, 0, stream>>>(bias, out);
        dim3 grid((N_PTS + PPB - 1) / PPB, KOFF);
        scatter_conv_kernel<<<grid, 256, 0, stream>>>(
            feat, weight, indice_pairs, indice_pair_num, out);
    }
}